// Round 4
// baseline (34.723 us; speedup 1.0000x reference)
//
#include <hip/hip_runtime.h>

#define IMG_H 512
#define IMG_W 512
#define NB    32
#define HW    (IMG_H * IMG_W)
#define SEGS  16             // 32-px segments per row
#define RPB   16             // rows per block (256 threads / 16 segs)
#define GX    (IMG_H / RPB)  // 32 blocks in x
#define NPART GX             // partials per batch

struct MPair { unsigned long long m1, m2; };

__device__ __forceinline__ MPair build_masks(const int* __restrict__ row) {
    unsigned long long m1 = 0ull, m2 = 0ull;
    #pragma unroll
    for (int q = 0; q < 8; ++q) {
        const int4 w = *reinterpret_cast<const int4*>(row + 4 * q);
        m1 |= ((unsigned long long)(w.x == 1)) << (4 * q + 0);
        m1 |= ((unsigned long long)(w.y == 1)) << (4 * q + 1);
        m1 |= ((unsigned long long)(w.z == 1)) << (4 * q + 2);
        m1 |= ((unsigned long long)(w.w == 1)) << (4 * q + 3);
        m2 |= ((unsigned long long)(w.x == 2)) << (4 * q + 0);
        m2 |= ((unsigned long long)(w.y == 2)) << (4 * q + 1);
        m2 |= ((unsigned long long)(w.z == 2)) << (4 * q + 2);
        m2 |= ((unsigned long long)(w.w == 2)) << (4 * q + 3);
    }
    MPair p; p.m1 = m1; p.m2 = m2; return p;
}

// Block tile: 16 rows x 512 cols. Each thread owns a 32-px segment of one row.
// y is loaded ONCE per row (phase 1 -> LDS masks); phase 2 combines 3x3 from LDS.
__global__ __launch_bounds__(256) void iou_kernel(const float* __restrict__ yhat,
                                                  const int* __restrict__ y,
                                                  unsigned long long* __restrict__ part) {
    const int b   = blockIdx.y;
    const int rl  = threadIdx.x >> 4;              // row in block 0..15
    const int seg = threadIdx.x & 15;
    const int h   = blockIdx.x * RPB + rl;         // global row (always valid)
    const int wb  = seg << 5;                      // *32

    const int* yb = y + (size_t)b * HW;

    __shared__ MPair masks[RPB + 2][SEGS];         // rows -1..16 at index 0..17

    // ---- Phase 1: own-row masks (+ halo rows by threads 0..31) ----
    masks[rl + 1][seg] = build_masks(yb + (size_t)h * IMG_W + wb);
    if (threadIdx.x < 2 * SEGS) {
        const int s  = threadIdx.x;
        const int hr = (s < SEGS) ? (blockIdx.x * RPB - 1) : (blockIdx.x * RPB + RPB);
        const int sg = s & 15;
        const int R  = (s < SEGS) ? 0 : (RPB + 1);
        if ((unsigned)hr < IMG_H)
            masks[R][sg] = build_masks(yb + (size_t)hr * IMG_W + (sg << 5));
    }
    __syncthreads();

    // ---- Phase 2: 3x3 erode/dilate from LDS masks ----
    // ext bit j = column wb-1+j (j=0..33). AND identity 1, OR identity 0.
    unsigned long long andv1 = ~0ull, orv1 = 0ull, andv2 = ~0ull, orv2 = 0ull;
    const int sL = (seg > 0) ? seg - 1 : 0;
    const int sR = (seg < SEGS - 1) ? seg + 1 : SEGS - 1;

    #pragma unroll
    for (int dr = -1; dr <= 1; ++dr) {
        const int R = rl + 1 + dr;
        const bool rv = (unsigned)(h + dr) < IMG_H;
        const MPair mc = masks[R][seg];
        const MPair mL = masks[R][sL];
        const MPair mR = masks[R][sR];

        const unsigned long long l1 = (mL.m1 >> 31) & 1ull;  // left seg col 31
        const unsigned long long l2 = (mL.m2 >> 31) & 1ull;
        const unsigned long long r1 = mR.m1 & 1ull;          // right seg col 0
        const unsigned long long r2 = mR.m2 & 1ull;

        const unsigned long long lA1 = (seg > 0) ? l1 : 1ull;
        const unsigned long long lO1 = (seg > 0) ? l1 : 0ull;
        const unsigned long long rA1 = (seg < SEGS - 1) ? r1 : 1ull;
        const unsigned long long rO1 = (seg < SEGS - 1) ? r1 : 0ull;
        const unsigned long long lA2 = (seg > 0) ? l2 : 1ull;
        const unsigned long long lO2 = (seg > 0) ? l2 : 0ull;
        const unsigned long long rA2 = (seg < SEGS - 1) ? r2 : 1ull;
        const unsigned long long rO2 = (seg < SEGS - 1) ? r2 : 0ull;

        const unsigned long long b1 = mc.m1 << 1;
        const unsigned long long b2 = mc.m2 << 1;

        andv1 &= rv ? (b1 | lA1 | (rA1 << 33)) : ~0ull;
        orv1  |= rv ? (b1 | lO1 | (rO1 << 33)) : 0ull;
        andv2 &= rv ? (b2 | lA2 | (rA2 << 33)) : ~0ull;
        orv2  |= rv ? (b2 | lO2 | (rO2 << 33)) : 0ull;
    }

    // pixel p (0..31) <- ext bits p, p+1, p+2
    const unsigned long long E1 = andv1 & (andv1 >> 1) & (andv1 >> 2);
    const unsigned long long E2 = andv2 & (andv2 >> 1) & (andv2 >> 2);
    const unsigned long long D1 = orv1  | (orv1  >> 1) | (orv1  >> 2);
    const unsigned long long D2 = orv2  | (orv2  >> 1) | (orv2  >> 2);

    // ---- Argmax over 3 channels -> class bitmasks (32 px, in 2 halves) ----
    const float* yh = yhat + (size_t)b * 3 * HW + (size_t)h * IMG_W + wb;
    unsigned long long P1 = 0ull, P2 = 0ull;
    #pragma unroll
    for (int half = 0; half < 2; ++half) {
        const float* p0 = yh + 16 * half;
        float A[16], Bv[16], Cv[16];
        #pragma unroll
        for (int q = 0; q < 4; ++q) {
            const float4 va = *reinterpret_cast<const float4*>(p0 + 4 * q);
            const float4 vb = *reinterpret_cast<const float4*>(p0 + HW + 4 * q);
            const float4 vc = *reinterpret_cast<const float4*>(p0 + 2 * HW + 4 * q);
            A[4*q+0]=va.x; A[4*q+1]=va.y; A[4*q+2]=va.z; A[4*q+3]=va.w;
            Bv[4*q+0]=vb.x; Bv[4*q+1]=vb.y; Bv[4*q+2]=vb.z; Bv[4*q+3]=vb.w;
            Cv[4*q+0]=vc.x; Cv[4*q+1]=vc.y; Cv[4*q+2]=vc.z; Cv[4*q+3]=vc.w;
        }
        unsigned p1 = 0u, p2 = 0u;
        #pragma unroll
        for (int j = 0; j < 16; ++j) {
            int   p    = 0;
            float best = A[j];
            if (Bv[j] > best) { best = Bv[j]; p = 1; }
            if (Cv[j] > best) {               p = 2; }
            p1 |= ((p == 1) ? 1u : 0u) << j;
            p2 |= ((p == 2) ? 1u : 0u) << j;
        }
        P1 |= ((unsigned long long)p1) << (16 * half);
        P2 |= ((unsigned long long)p2) << (16 * half);
    }

    // inter: dil = D2?2:(D1?1:0); hit where dil==prob && dil!=0
    const unsigned long long PIX = 0xFFFFFFFFull;
    const unsigned inter = (unsigned)__popcll(((D2 & P2) | (D1 & ~D2 & P1)) & PIX);
    const unsigned uni   = (unsigned)__popcll((E1 | E2 | P1 | P2) & PIX);

    // ---- Reduce: wave -> block -> one store per block ----
    unsigned long long packed = (unsigned long long)inter | ((unsigned long long)uni << 32);
    #pragma unroll
    for (int off = 32; off > 0; off >>= 1)
        packed += __shfl_down(packed, off, 64);

    __shared__ unsigned long long wsum[4];
    const int wave = threadIdx.x >> 6;
    if ((threadIdx.x & 63) == 0) wsum[wave] = packed;
    __syncthreads();
    if (threadIdx.x == 0)
        part[(size_t)b * NPART + blockIdx.x] = wsum[0] + wsum[1] + wsum[2] + wsum[3];
}

__global__ void finalize_kernel(const unsigned long long* __restrict__ part,
                                float* __restrict__ out) {
    // 256 threads: 8 threads per batch, each sums 4 of the 32 partials.
    const int t = threadIdx.x;
    const int b = t >> 3;
    const int k = t & 7;
    unsigned long long s = 0ull;
    #pragma unroll
    for (int i = 0; i < 4; ++i)
        s += part[(size_t)b * NPART + k * 4 + i];
    s += __shfl_down(s, 4, 8);
    s += __shfl_down(s, 2, 8);
    s += __shfl_down(s, 1, 8);

    __shared__ float r[NB];
    if (k == 0) {
        const float inter = (float)(unsigned int)(s & 0xFFFFFFFFull);
        const float uni   = (float)(unsigned int)(s >> 32);
        r[b] = inter / uni;
    }
    __syncthreads();
    if (t < 32) {
        float v = r[t];
        #pragma unroll
        for (int off = 16; off > 0; off >>= 1)
            v += __shfl_down(v, off, 32);
        if (t == 0) out[0] = v / (float)NB;
    }
}

extern "C" void kernel_launch(void* const* d_in, const int* in_sizes, int n_in,
                              void* d_out, int out_size, void* d_ws, size_t ws_size,
                              hipStream_t stream) {
    const float* yhat = (const float*)d_in[0];
    const int*   y    = (const int*)d_in[1];
    float*       out  = (float*)d_out;
    unsigned long long* part = (unsigned long long*)d_ws;   // 32*32 u64 = 8 KB

    dim3 grid(GX, NB, 1);
    iou_kernel<<<grid, 256, 0, stream>>>(yhat, y, part);
    finalize_kernel<<<1, 256, 0, stream>>>(part, out);
}

// Round 5
// 29.045 us; speedup vs baseline: 1.1955x; 1.1955x over previous
//
#include <hip/hip_runtime.h>

#define IMG_H 512
#define IMG_W 512
#define NB    32
#define HW    (IMG_H * IMG_W)
#define SEGS  32             // 16-px segments per row
#define RPB   8              // rows per block (256 threads / 32 segs)
#define GX    (IMG_H / RPB)  // 64 blocks in x
#define NPART GX             // partials per batch

// Build packed class masks for 16 px: bits 0..15 = (y==1), bits 16..31 = (y==2).
__device__ __forceinline__ unsigned build16(const int* __restrict__ row) {
    unsigned m = 0u;
    #pragma unroll
    for (int q = 0; q < 4; ++q) {
        const int4 w = *reinterpret_cast<const int4*>(row + 4 * q);
        m |= ((w.x == 1) ? 1u : 0u) << (4 * q + 0);
        m |= ((w.y == 1) ? 1u : 0u) << (4 * q + 1);
        m |= ((w.z == 1) ? 1u : 0u) << (4 * q + 2);
        m |= ((w.w == 1) ? 1u : 0u) << (4 * q + 3);
        m |= ((w.x == 2) ? 1u : 0u) << (16 + 4 * q + 0);
        m |= ((w.y == 2) ? 1u : 0u) << (16 + 4 * q + 1);
        m |= ((w.z == 2) ? 1u : 0u) << (16 + 4 * q + 2);
        m |= ((w.w == 2) ? 1u : 0u) << (16 + 4 * q + 3);
    }
    return m;
}

// Each thread: one 16-pixel row segment. Wave = 2 adjacent rows x 32 segs.
// Own + outward row masks built locally; the third row comes from shfl(lane^32).
__global__ __launch_bounds__(256) void iou_kernel(const float* __restrict__ yhat,
                                                  const int* __restrict__ y,
                                                  unsigned long long* __restrict__ part) {
    const int b   = blockIdx.y;
    const int t   = blockIdx.x * 256 + threadIdx.x;
    const int h   = t >> 5;                 // row
    const int seg = t & 31;
    const int wbase = seg << 4;             // *16

    const int lane    = threadIdx.x & 63;
    const bool lowHalf = (lane < 32);       // lanes 0-31: rows H0; 32-63: H0+1

    // ---- Issue the dominant yhat stream FIRST (12 independent float4) ----
    const float* yh = yhat + (size_t)b * 3 * HW + (size_t)h * IMG_W + wbase;
    float4 qa0 = *reinterpret_cast<const float4*>(yh);
    float4 qa1 = *reinterpret_cast<const float4*>(yh + 4);
    float4 qa2 = *reinterpret_cast<const float4*>(yh + 8);
    float4 qa3 = *reinterpret_cast<const float4*>(yh + 12);
    float4 qb0 = *reinterpret_cast<const float4*>(yh + HW);
    float4 qb1 = *reinterpret_cast<const float4*>(yh + HW + 4);
    float4 qb2 = *reinterpret_cast<const float4*>(yh + HW + 8);
    float4 qb3 = *reinterpret_cast<const float4*>(yh + HW + 12);
    float4 qc0 = *reinterpret_cast<const float4*>(yh + 2 * HW);
    float4 qc1 = *reinterpret_cast<const float4*>(yh + 2 * HW + 4);
    float4 qc2 = *reinterpret_cast<const float4*>(yh + 2 * HW + 8);
    float4 qc3 = *reinterpret_cast<const float4*>(yh + 2 * HW + 12);

    // ---- y masks: own row + outward row; partner supplies the third ----
    const int* yb = y + (size_t)b * HW;
    const int ho  = lowHalf ? (h - 1) : (h + 1);            // outward row
    const bool ov = (unsigned)ho < IMG_H;                   // outward validity
    const int hoc = ov ? ho : h;                            // clamped (load always legal)

    const unsigned mOwn = build16(yb + (size_t)h   * IMG_W + wbase);
    const unsigned mOut = build16(yb + (size_t)hoc * IMG_W + wbase);
    const unsigned mPar = __shfl(mOwn, lane ^ 32, 64);      // partner row (h+1 or h-1)

    // Assemble top/mid/bot for this thread's row h.
    const unsigned mT = lowHalf ? mOut : mPar;
    const unsigned mB = lowHalf ? mPar : mOut;
    const bool vT = lowHalf ? ov : true;                    // h-1 validity
    const bool vB = lowHalf ? true : ov;                    // h+1 validity

    // ---- L/R halo shuffles (6, batched; one wait covers all) ----
    const int laneL = (lane + 63) & 63;  // cross-half leakage only at seg borders (masked)
    const int laneR = (lane + 1) & 63;
    const unsigned tL = __shfl(mT, laneL, 64), tR = __shfl(mT, laneR, 64);
    const unsigned cL = __shfl(mOwn, laneL, 64), cR = __shfl(mOwn, laneR, 64);
    const unsigned bL = __shfl(mB, laneL, 64), bR = __shfl(mB, laneR, 64);

    // ext bit j = column wbase-1+j (j=0..17): ext = (m<<1) | leftbit | rightbit<<17
    #define EXT1(m, ml, mr) ((((m) & 0xFFFFu) << 1) | (((ml) >> 15) & 1u) | (((mr) & 1u) << 17))
    #define EXT2(m, ml, mr) ((((m) >> 16) << 1)     | ((ml) >> 31)        | ((((mr) >> 16) & 1u) << 17))
    const unsigned eT1 = EXT1(mT, tL, tR),   eT2 = EXT2(mT, tL, tR);
    const unsigned eC1 = EXT1(mOwn, cL, cR), eC2 = EXT2(mOwn, cL, cR);
    const unsigned eB1 = EXT1(mB, bL, bR),   eB2 = EXT2(mB, bL, bR);

    const unsigned ALL = 0x3FFFFu;
    unsigned vmask = ALL;
    if (seg == 0)        vmask &= ~1u;
    if (seg == SEGS - 1) vmask &= ~(1u << 17);
    const unsigned inv = ALL & ~vmask;

    unsigned and1 = eC1 & (vT ? eT1 : ALL) & (vB ? eB1 : ALL);
    unsigned and2 = eC2 & (vT ? eT2 : ALL) & (vB ? eB2 : ALL);
    unsigned or1  = eC1 | (vT ? eT1 : 0u)  | (vB ? eB1 : 0u);
    unsigned or2  = eC2 | (vT ? eT2 : 0u)  | (vB ? eB2 : 0u);
    and1 |= inv;  and2 |= inv;
    or1  &= vmask; or2 &= vmask;

    // pixel j <- ext bits j, j+1, j+2
    const unsigned E1 = and1 & (and1 >> 1) & (and1 >> 2);
    const unsigned E2 = and2 & (and2 >> 1) & (and2 >> 2);
    const unsigned D1 = or1  | (or1  >> 1) | (or1  >> 2);
    const unsigned D2 = or2  | (or2  >> 1) | (or2  >> 2);

    // ---- Argmax -> class bitmasks (loads issued long ago) ----
    float A[16]  = {qa0.x,qa0.y,qa0.z,qa0.w, qa1.x,qa1.y,qa1.z,qa1.w,
                    qa2.x,qa2.y,qa2.z,qa2.w, qa3.x,qa3.y,qa3.z,qa3.w};
    float Bv[16] = {qb0.x,qb0.y,qb0.z,qb0.w, qb1.x,qb1.y,qb1.z,qb1.w,
                    qb2.x,qb2.y,qb2.z,qb2.w, qb3.x,qb3.y,qb3.z,qb3.w};
    float Cv[16] = {qc0.x,qc0.y,qc0.z,qc0.w, qc1.x,qc1.y,qc1.z,qc1.w,
                    qc2.x,qc2.y,qc2.z,qc2.w, qc3.x,qc3.y,qc3.z,qc3.w};
    unsigned P1 = 0u, P2 = 0u;
    #pragma unroll
    for (int j = 0; j < 16; ++j) {
        int   p    = 0;
        float best = A[j];
        if (Bv[j] > best) { best = Bv[j]; p = 1; }
        if (Cv[j] > best) {               p = 2; }
        P1 |= ((p == 1) ? 1u : 0u) << j;
        P2 |= ((p == 2) ? 1u : 0u) << j;
    }

    const unsigned inter = (unsigned)__popc((D2 & P2) | (D1 & ~D2 & P1));
    const unsigned uni   = (unsigned)__popc((E1 | E2 | P1 | P2) & 0xFFFFu);

    // ---- Reduce: wave -> block -> one store per block ----
    unsigned long long packed = (unsigned long long)inter | ((unsigned long long)uni << 32);
    #pragma unroll
    for (int off = 32; off > 0; off >>= 1)
        packed += __shfl_down(packed, off, 64);

    __shared__ unsigned long long wsum[4];
    const int wave = threadIdx.x >> 6;
    if ((threadIdx.x & 63) == 0) wsum[wave] = packed;
    __syncthreads();
    if (threadIdx.x == 0)
        part[(size_t)b * NPART + blockIdx.x] = wsum[0] + wsum[1] + wsum[2] + wsum[3];
}

__global__ void finalize_kernel(const unsigned long long* __restrict__ part,
                                float* __restrict__ out) {
    // 256 threads: 8 threads per batch, each sums 8 of the 64 partials.
    const int t = threadIdx.x;
    const int b = t >> 3;
    const int k = t & 7;
    unsigned long long s = 0ull;
    #pragma unroll
    for (int i = 0; i < 8; ++i)
        s += part[(size_t)b * NPART + k * 8 + i];
    s += __shfl_down(s, 4, 8);
    s += __shfl_down(s, 2, 8);
    s += __shfl_down(s, 1, 8);

    __shared__ float r[NB];
    if (k == 0) {
        const float inter = (float)(unsigned int)(s & 0xFFFFFFFFull);
        const float uni   = (float)(unsigned int)(s >> 32);
        r[b] = inter / uni;
    }
    __syncthreads();
    if (t < 32) {
        float v = r[t];
        #pragma unroll
        for (int off = 16; off > 0; off >>= 1)
            v += __shfl_down(v, off, 32);
        if (t == 0) out[0] = v / (float)NB;
    }
}

extern "C" void kernel_launch(void* const* d_in, const int* in_sizes, int n_in,
                              void* d_out, int out_size, void* d_ws, size_t ws_size,
                              hipStream_t stream) {
    const float* yhat = (const float*)d_in[0];
    const int*   y    = (const int*)d_in[1];
    float*       out  = (float*)d_out;
    unsigned long long* part = (unsigned long long*)d_ws;   // 32*64 u64 = 16 KB

    dim3 grid(GX, NB, 1);
    iou_kernel<<<grid, 256, 0, stream>>>(yhat, y, part);
    finalize_kernel<<<1, 256, 0, stream>>>(part, out);
}